// Round 4
// baseline (10769.900 us; speedup 1.0000x reference)
//
#include <hip/hip_runtime.h>

// RecurrentTransformerEncoder on MI355X — round 12: phase 2 re-architected as
// 64 INDEPENDENT per-sequence chains (the connection step never mixes batch
// elements). One 1024-thread block per sequence runs all 15 steps with the
// 50x512 recurrent state resident in LDS; per-stage sync is __syncthreads()
// only (no grid barriers, no device fences — rounds 9-11 showed those cost
// 35-65us each). Per-block scratch in global is block-private -> L2-resident.
// Phase 1 unchanged. B=64, T=16, SEG=50, E=D=512, H=8, DH=64, F=2048.

#define NB   64
#define NT   16
#define SEGL 50
#define DMODEL 512
#define DFF  2048
#define NHEAD 8
#define DHEAD 64

typedef unsigned short ushort_t;
typedef __attribute__((ext_vector_type(8))) short bfrag;   // 8 bf16 (4 VGPRs)
typedef __attribute__((ext_vector_type(4))) float ffrag;   // 4 fp32 acc

__device__ __forceinline__ ushort_t f2b(float x) {
    union { float f; unsigned u; } c; c.f = x;
    unsigned r = c.u + 0x7fffu + ((c.u >> 16) & 1u);
    return (ushort_t)(r >> 16);
}

#define GLOAD_LDS16(g, l) __builtin_amdgcn_global_load_lds( \
    (const __attribute__((address_space(1))) void*)(g),      \
    (__attribute__((address_space(3))) void*)(l), 16, 0, 0)

#define MFMA16(a, b, c) __builtin_amdgcn_mfma_f32_16x16x32_bf16(a, b, c, 0, 0, 0)

// ---------------------------------------------------------------------------
// MFMA GEMM (LDS-staged, BK=64 dbuf): C = relu?(A @ Bt^T), bf16.  (phase 1)
// ---------------------------------------------------------------------------
template<int BM, int BN, int WROWS, int WCOLS>
__global__ __launch_bounds__(256) void mfma_gemm(
    const ushort_t* __restrict__ A, int agrp, long long astride,
    const ushort_t* __restrict__ Bt, ushort_t* __restrict__ C,
    int M, int N, int K, int relu)
{
    constexpr int WM = BM / WROWS, WN = BN / WCOLS;
    constexpr int SM = WM / 16, SN = WN / 16;
    constexpr int NSUBA = BM / 16, NSUBB = BN / 16;
    constexpr int NSUB = NSUBA + NSUBB;
    constexpr int NINST = NSUB * 2;
    constexpr int IPW = NINST / 4;
    constexpr int BUFS = NSUB * 1024;
    constexpr int EST = WN + 8;
    constexpr int LDS_KLOOP = 2 * BUFS;
    constexpr int LDS_EPI   = 4 * WM * EST;
    constexpr int LDS_SZ = LDS_KLOOP > LDS_EPI ? LDS_KLOOP : LDS_EPI;
    __shared__ ushort_t lds[LDS_SZ];

    const int tid = threadIdx.x;
    const int wave = tid >> 6, lane = tid & 63;
    const int wrow = wave / WCOLS, wcol = wave % WCOLS;
    const int bm = blockIdx.y * BM, bn = blockIdx.x * BN;
    const int lm = lane & 15, lq = lane >> 4;

    ffrag acc[SM][SN];
#pragma unroll
    for (int i = 0; i < SM; ++i)
#pragma unroll
        for (int j = 0; j < SN; ++j) acc[i][j] = (ffrag){0.f, 0.f, 0.f, 0.f};

    const ushort_t* gptr[IPW];
    int loff[IPW];
#pragma unroll
    for (int e = 0; e < IPW; ++e) {
        int g = wave * IPW + e;
        int s = g >> 1, h = g & 1;
        if (s < NSUBA) {
            int m = bm + s * 16 + lm;
            gptr[e] = A + (long long)(m / agrp) * astride
                        + (long long)(m % agrp) * K + h * 32 + lq * 8;
        } else {
            int n = bn + (s - NSUBA) * 16 + lm;
            gptr[e] = Bt + (long long)n * K + h * 32 + lq * 8;
        }
        loff[e] = s * 1024 + h * 512;
    }

#pragma unroll
    for (int e = 0; e < IPW; ++e)
        GLOAD_LDS16(gptr[e], &lds[loff[e]]);

    const int nk = K >> 6;
    for (int kk = 0; kk < nk; ++kk) {
        __syncthreads();
        if (kk + 1 < nk) {
            const int koff = (kk + 1) << 6;
            const int nb = (kk + 1) & 1;
#pragma unroll
            for (int e = 0; e < IPW; ++e)
                GLOAD_LDS16(gptr[e] + koff, &lds[nb * BUFS + loff[e]]);
        }
        const ushort_t* lb = &lds[(kk & 1) * BUFS];
#pragma unroll
        for (int h = 0; h < 2; ++h) {
            bfrag af[SM], bfg[SN];
#pragma unroll
            for (int i = 0; i < SM; ++i)
                af[i] = *(const bfrag*)&lb[(wrow * SM + i) * 1024 + h * 512 + lane * 8];
#pragma unroll
            for (int j = 0; j < SN; ++j)
                bfg[j] = *(const bfrag*)&lb[(NSUBA + wcol * SN + j) * 1024 + h * 512 + lane * 8];
#pragma unroll
            for (int i = 0; i < SM; ++i)
#pragma unroll
                for (int j = 0; j < SN; ++j)
                    acc[i][j] = MFMA16(af[i], bfg[j], acc[i][j]);
        }
    }

    __syncthreads();
    ushort_t* ep = &lds[wave * WM * EST];
#pragma unroll
    for (int i = 0; i < SM; ++i)
#pragma unroll
        for (int j = 0; j < SN; ++j)
#pragma unroll
            for (int r = 0; r < 4; ++r) {
                int row = i * 16 + lq * 4 + r;
                int col = j * 16 + lm;
                float v = acc[i][j][r];
                if (relu) v = fmaxf(v, 0.f);
                ep[row * EST + col] = f2b(v);
            }
    constexpr int CPR = WN / 8;
    constexpr int RPI = 64 / CPR;
    const int lrow = lane / CPR, lcol = (lane % CPR) * 8;
#pragma unroll
    for (int it = 0; it < WM / RPI; ++it) {
        int row = it * RPI + lrow;
        uint4 v = *(const uint4*)&ep[row * EST + lcol];
        long long grow = bm + wrow * WM + row;
        int gcol = bn + wcol * WN + lcol;
        *(uint4*)&C[grow * N + gcol] = v;
    }
}

// ---------------------------------------------------------------------------
__global__ __launch_bounds__(256) void wtrans_k(
    const float* __restrict__ W, ushort_t* __restrict__ Wt, int K, int N)
{
    __shared__ float t[32][33];
    const int bk = blockIdx.y * 32, bn = blockIdx.x * 32;
    const int tx = threadIdx.x & 31, ty = threadIdx.x >> 5;
    for (int i = ty; i < 32; i += 8)
        t[i][tx] = W[(long long)(bk + i) * N + bn + tx];
    __syncthreads();
    for (int i = ty; i < 32; i += 8)
        Wt[(long long)(bn + i) * K + bk + tx] = f2b(t[tx][i]);
}

__global__ __launch_bounds__(256) void cvt_k(
    const float* __restrict__ in, ushort_t* __restrict__ out, long long n)
{
    long long i = ((long long)blockIdx.x * 256 + threadIdx.x) * 8;
    if (i >= n) return;
    float4 a = *(const float4*)(in + i);
    float4 b = *(const float4*)(in + i + 4);
    ushort_t o[8] = {f2b(a.x), f2b(a.y), f2b(a.z), f2b(a.w),
                     f2b(b.x), f2b(b.y), f2b(b.z), f2b(b.w)};
    *(uint4*)(out + i) = *(const uint4*)o;
}

// ---------------------------------------------------------------------------
// Phase-1 MFMA attention, one (sequence n, head h) per block. S=50->64, D=64.
// ---------------------------------------------------------------------------
__global__ __launch_bounds__(256) void attn_mfma_k(
    const ushort_t* __restrict__ Q, long long qns, long long qrs,
    const ushort_t* __restrict__ K, const ushort_t* __restrict__ V,
    long long kns, long long kvrs,
    ushort_t* __restrict__ O,
    const int* __restrict__ lens, int G, int t0)
{
    __shared__ ushort_t qs[64][72];   // Q, then P
    __shared__ ushort_t ks[64][72];
    __shared__ ushort_t vt[64][72];   // V^T
    const int n = blockIdx.x >> 3, h = blockIdx.x & 7;
    const int tid = threadIdx.x;
    const int wave = tid >> 6, lane = tid & 63;
    const int lm = lane & 15, lq = lane >> 4;
    int len = SEGL;
    if (lens) {
        int b = n / G, t = t0 + (n % G);
        len = lens[b * NT + t];
        if (len > SEGL) len = SEGL;
    }
    {
        uint4 z = {0, 0, 0, 0};
        uint4* vz = (uint4*)&vt[0][0];
        for (int i = tid; i < 64 * 72 / 8; i += 256) vz[i] = z;
    }
    __syncthreads();
    for (int idx = tid; idx < SEGL * 8; idx += 256) {
        int s = idx >> 3, d8 = (idx & 7) << 3;
        const ushort_t* qp = Q + (long long)n * qns + (long long)s * qrs + h * DHEAD + d8;
        const ushort_t* kp = K + (long long)n * kns + (long long)s * kvrs + h * DHEAD + d8;
        const ushort_t* vp = V + (long long)n * kns + (long long)s * kvrs + h * DHEAD + d8;
        *(uint4*)&qs[s][d8] = *(const uint4*)qp;
        *(uint4*)&ks[s][d8] = *(const uint4*)kp;
        uint4 v4 = *(const uint4*)vp;
        const ushort_t* vv = (const ushort_t*)&v4;
#pragma unroll
        for (int u = 0; u < 8; ++u) vt[d8 + u][s] = vv[u];
    }
    __syncthreads();

    ffrag sc[4];
#pragma unroll
    for (int nt = 0; nt < 4; ++nt) sc[nt] = (ffrag){0.f, 0.f, 0.f, 0.f};
#pragma unroll
    for (int kt = 0; kt < 2; ++kt) {
        bfrag a = *(const bfrag*)&qs[wave * 16 + lm][kt * 32 + lq * 8];
#pragma unroll
        for (int nt = 0; nt < 4; ++nt) {
            bfrag b = *(const bfrag*)&ks[nt * 16 + lm][kt * 32 + lq * 8];
            sc[nt] = MFMA16(a, b, sc[nt]);
        }
    }
    __syncthreads();

#pragma unroll
    for (int r = 0; r < 4; ++r) {
        float x[4];
        float mx = -1e30f;
#pragma unroll
        for (int nt = 0; nt < 4; ++nt) {
            int col = nt * 16 + lm;
            x[nt] = (col < len) ? sc[nt][r] * 0.125f : -1e9f;
            mx = fmaxf(mx, x[nt]);
        }
        for (int off = 8; off; off >>= 1) mx = fmaxf(mx, __shfl_xor(mx, off));
        float e[4], se = 0.f;
#pragma unroll
        for (int nt = 0; nt < 4; ++nt) { e[nt] = __expf(x[nt] - mx); se += e[nt]; }
        for (int off = 8; off; off >>= 1) se += __shfl_xor(se, off);
        float inv = 1.f / se;
        int row = wave * 16 + lq * 4 + r;
#pragma unroll
        for (int nt = 0; nt < 4; ++nt)
            qs[row][nt * 16 + lm] = f2b(e[nt] * inv);
    }
    __syncthreads();

    ffrag oc[4];
#pragma unroll
    for (int dt = 0; dt < 4; ++dt) oc[dt] = (ffrag){0.f, 0.f, 0.f, 0.f};
#pragma unroll
    for (int kt = 0; kt < 2; ++kt) {
        bfrag a = *(const bfrag*)&qs[wave * 16 + lm][kt * 32 + lq * 8];
#pragma unroll
        for (int dt = 0; dt < 4; ++dt) {
            bfrag b = *(const bfrag*)&vt[dt * 16 + lm][kt * 32 + lq * 8];
            oc[dt] = MFMA16(a, b, oc[dt]);
        }
    }
#pragma unroll
    for (int r = 0; r < 4; ++r) {
        int i = wave * 16 + lq * 4 + r;
        if (i < SEGL) {
            ushort_t* op = O + (long long)(n * SEGL + i) * DMODEL + h * DHEAD + lm;
#pragma unroll
            for (int dt = 0; dt < 4; ++dt)
                op[dt * 16] = f2b(oc[dt][r]);
        }
    }
}

// ---------------------------------------------------------------------------
// out = LN(a + b)*gamma + beta, rows of 512, bf16 in, bf16/fp32 out. (phase 1)
// ---------------------------------------------------------------------------
template<bool OUTF32>
__global__ __launch_bounds__(256) void add_ln_k(
    const ushort_t* __restrict__ A, int agrp, long long astride,
    const ushort_t* __restrict__ Bv,
    const float* __restrict__ gamma, const float* __restrict__ beta,
    void* __restrict__ O, int ogrp, long long ostride, int M)
{
    const int wave = threadIdx.x >> 6, lane = threadIdx.x & 63;
    const int r = blockIdx.x * 4 + wave;
    if (r >= M) return;
    const ushort_t* a = A + (long long)(r / agrp) * astride + (long long)(r % agrp) * DMODEL;
    const ushort_t* b = Bv + (long long)r * DMODEL;
    float x[8];
    {
        uint4 a4 = *(const uint4*)(a + lane * 8);
        uint4 b4 = *(const uint4*)(b + lane * 8);
        const unsigned* aa = (const unsigned*)&a4;
        const unsigned* bb = (const unsigned*)&b4;
#pragma unroll
        for (int c = 0; c < 4; ++c) {
            union { unsigned u; float f; } alo, ahi, blo, bhi;
            alo.u = aa[c] << 16; ahi.u = aa[c] & 0xffff0000u;
            blo.u = bb[c] << 16; bhi.u = bb[c] & 0xffff0000u;
            x[2 * c]     = alo.f + blo.f;
            x[2 * c + 1] = ahi.f + bhi.f;
        }
    }
    float s = 0.f, s2 = 0.f;
#pragma unroll
    for (int i = 0; i < 8; ++i) { s += x[i]; s2 = fmaf(x[i], x[i], s2); }
    for (int off = 32; off; off >>= 1) {
        s += __shfl_xor(s, off);
        s2 += __shfl_xor(s2, off);
    }
    const float mean = s * (1.f / DMODEL);
    const float var = s2 * (1.f / DMODEL) - mean * mean;
    const float inv = rsqrtf(var + 1e-5f);
    float4 g0 = *(const float4*)(gamma + lane * 8);
    float4 g1 = *(const float4*)(gamma + lane * 8 + 4);
    float4 be0 = *(const float4*)(beta + lane * 8);
    float4 be1 = *(const float4*)(beta + lane * 8 + 4);
    float y[8];
    y[0] = (x[0] - mean) * inv * g0.x + be0.x;
    y[1] = (x[1] - mean) * inv * g0.y + be0.y;
    y[2] = (x[2] - mean) * inv * g0.z + be0.z;
    y[3] = (x[3] - mean) * inv * g0.w + be0.w;
    y[4] = (x[4] - mean) * inv * g1.x + be1.x;
    y[5] = (x[5] - mean) * inv * g1.y + be1.y;
    y[6] = (x[6] - mean) * inv * g1.z + be1.z;
    y[7] = (x[7] - mean) * inv * g1.w + be1.w;
    if (OUTF32) {
        float* o = (float*)O + (long long)(r / ogrp) * ostride + (long long)(r % ogrp) * DMODEL;
        *(float4*)(o + lane * 8) = *(float4*)&y[0];
        *(float4*)(o + lane * 8 + 4) = *(float4*)&y[4];
    } else {
        ushort_t* o = (ushort_t*)O + (long long)(r / ogrp) * ostride + (long long)(r % ogrp) * DMODEL;
        ushort_t ob[8];
#pragma unroll
        for (int i = 0; i < 8; ++i) ob[i] = f2b(y[i]);
        *(uint4*)(o + lane * 8) = *(const uint4*)ob;
    }
}

__global__ void lens_k(const int* __restrict__ ends, int* __restrict__ lens)
{
    int i = blockIdx.x * 256 + threadIdx.x;
    if (i >= NB * NT) return;
    int t = i & (NT - 1);
    int prev = t ? ends[i - 1] : 0;
    int l = ends[i] - prev;
    if (l > SEGL) l = SEGL;
    lens[i] = l;
}

// ===========================================================================
// Phase 2: one block per sequence, 1024 threads (16 waves), all 15 steps.
// Recurrent state P (50x512, padded [64][520]) lives in LDS. Per-block global
// scratch (block-private -> L2): Kg[64][512], VTg[512][64], Sg[8][64][64],
// ATg[64][512], Hg[64][512]. All MFMA epilogues write rows 0-63; garbage in
// pad rows stays in pad rows (row-wise dataflow); P pad rows are zeroed once
// and only rows<50 are ever rewritten.
// ===========================================================================
__global__ __launch_bounds__(1024) void phase2_seq(
    const ushort_t* __restrict__ ENC, const ushort_t* __restrict__ QALL,
    const ushort_t* __restrict__ Wkv, const ushort_t* __restrict__ WoT,
    const ushort_t* __restrict__ F1T, const ushort_t* __restrict__ F2T,
    const float* __restrict__ G1v, const float* __restrict__ B1v,
    const float* __restrict__ G2v, const float* __restrict__ B2v,
    ushort_t* __restrict__ SCR, float* __restrict__ out)
{
    extern __shared__ ushort_t lds[];
    ushort_t* Pb = lds;                  // [64][520], stride 1040B (16B-aligned)
    ushort_t* Mb = lds + 64 * 520;       // [64][264], stride 528B
    const int n = blockIdx.x;
    const int tid = threadIdx.x;
    const int w = tid >> 6, lane = tid & 63;
    const int lm = lane & 15, lq = lane >> 4;
    const int hh = w >> 1, wp = w & 1;   // head / wave-pair for attn phases

    ushort_t* Kg  = SCR + (long long)n * 163840;
    ushort_t* VTg = Kg + 32768;
    ushort_t* Sg  = Kg + 65536;
    ushort_t* ATg = Kg + 98304;
    ushort_t* Hg  = Kg + 131072;

    // init P: zero whole buffer (pads stay 0 forever), then rows 0-49 = ENC[n][0]
    {
        uint4 z = {0, 0, 0, 0};
        for (int i = tid; i < 64 * 520 / 8; i += 1024) ((uint4*)Pb)[i] = z;
    }
    __syncthreads();
    for (int idx = tid; idx < 50 * 64; idx += 1024) {
        int s = idx >> 6, c8 = (idx & 63) << 3;
        *(uint4*)&Pb[s * 520 + c8] =
            *(const uint4*)(ENC + (long long)n * 409600 + (long long)s * 512 + c8);
    }
    __syncthreads();

#pragma unroll 1
    for (int t = 1; t < NT; ++t) {
        const ushort_t* Qb = QALL + (long long)n * 384000 + (long long)(t - 1) * 25600;

        // ---- A1: K,V projection. C[64][512] each; A = P (LDS), B = Wkv rows.
        {
            ffrag ka[4][2], va[4][2];
#pragma unroll
            for (int i = 0; i < 4; ++i)
#pragma unroll
                for (int j = 0; j < 2; ++j) {
                    ka[i][j] = (ffrag){0.f, 0.f, 0.f, 0.f};
                    va[i][j] = (ffrag){0.f, 0.f, 0.f, 0.f};
                }
            const ushort_t* wk = Wkv + (long long)(w * 32) * 512;
            const ushort_t* wv = Wkv + (long long)(512 + w * 32) * 512;
#pragma unroll
            for (int k8 = 0; k8 < 16; ++k8) {
                bfrag af[4];
#pragma unroll
                for (int i = 0; i < 4; ++i)
                    af[i] = *(const bfrag*)&Pb[(i * 16 + lm) * 520 + k8 * 32 + lq * 8];
#pragma unroll
                for (int j = 0; j < 2; ++j) {
                    bfrag bk = *(const bfrag*)(wk + (long long)(j * 16 + lm) * 512 + k8 * 32 + lq * 8);
                    bfrag bv = *(const bfrag*)(wv + (long long)(j * 16 + lm) * 512 + k8 * 32 + lq * 8);
#pragma unroll
                    for (int i = 0; i < 4; ++i) {
                        ka[i][j] = MFMA16(af[i], bk, ka[i][j]);
                        va[i][j] = MFMA16(af[i], bv, va[i][j]);
                    }
                }
            }
#pragma unroll
            for (int i = 0; i < 4; ++i)
#pragma unroll
                for (int j = 0; j < 2; ++j)
#pragma unroll
                    for (int r = 0; r < 4; ++r) {
                        int row = i * 16 + lq * 4 + r;
                        int col = w * 32 + j * 16 + lm;
                        Kg[row * 512 + col] = f2b(ka[i][j][r]);
                        VTg[col * 64 + row] = f2b(va[i][j][r]);
                    }
        }
        __syncthreads();

        // ---- A2: QK^T + softmax for head hh (2 waves/head). S -> Sg[hh].
        {
            ffrag sc[2][4];
#pragma unroll
            for (int i = 0; i < 2; ++i)
#pragma unroll
                for (int j = 0; j < 4; ++j) sc[i][j] = (ffrag){0.f, 0.f, 0.f, 0.f};
#pragma unroll
            for (int kk = 0; kk < 2; ++kk) {
                bfrag aq[2];
#pragma unroll
                for (int ii = 0; ii < 2; ++ii)
                    aq[ii] = *(const bfrag*)(Qb + (long long)((wp * 2 + ii) * 16 + lm) * 512
                                             + hh * 64 + kk * 32 + lq * 8);
#pragma unroll
                for (int j = 0; j < 4; ++j) {
                    bfrag bk = *(const bfrag*)&Kg[(j * 16 + lm) * 512 + hh * 64 + kk * 32 + lq * 8];
#pragma unroll
                    for (int ii = 0; ii < 2; ++ii)
                        sc[ii][j] = MFMA16(aq[ii], bk, sc[ii][j]);
                }
            }
#pragma unroll
            for (int ii = 0; ii < 2; ++ii)
#pragma unroll
                for (int r = 0; r < 4; ++r) {
                    float x[4], mx = -1e30f;
#pragma unroll
                    for (int j = 0; j < 4; ++j) {
                        int col = j * 16 + lm;
                        x[j] = (col < SEGL) ? sc[ii][j][r] * 0.125f : -1e9f;
                        mx = fmaxf(mx, x[j]);
                    }
                    for (int off = 8; off; off >>= 1) mx = fmaxf(mx, __shfl_xor(mx, off));
                    float e[4], se = 0.f;
#pragma unroll
                    for (int j = 0; j < 4; ++j) { e[j] = __expf(x[j] - mx); se += e[j]; }
                    for (int off = 8; off; off >>= 1) se += __shfl_xor(se, off);
                    float inv = 1.f / se;
                    int row = (wp * 2 + ii) * 16 + lq * 4 + r;
#pragma unroll
                    for (int j = 0; j < 4; ++j)
                        Sg[hh * 4096 + row * 64 + j * 16 + lm] = f2b(e[j] * inv);
                }
        }
        __syncthreads();

        // ---- A3: PV for head hh. attn[:, hh*64..] -> ATg.
        {
            ffrag oc[2][4];
#pragma unroll
            for (int i = 0; i < 2; ++i)
#pragma unroll
                for (int j = 0; j < 4; ++j) oc[i][j] = (ffrag){0.f, 0.f, 0.f, 0.f};
#pragma unroll
            for (int kk = 0; kk < 2; ++kk) {
                bfrag as[2];
#pragma unroll
                for (int ii = 0; ii < 2; ++ii)
                    as[ii] = *(const bfrag*)&Sg[hh * 4096 + ((wp * 2 + ii) * 16 + lm) * 64
                                                + kk * 32 + lq * 8];
#pragma unroll
                for (int j = 0; j < 4; ++j) {
                    bfrag bv = *(const bfrag*)&VTg[(hh * 64 + j * 16 + lm) * 64 + kk * 32 + lq * 8];
#pragma unroll
                    for (int ii = 0; ii < 2; ++ii)
                        oc[ii][j] = MFMA16(as[ii], bv, oc[ii][j]);
                }
            }
#pragma unroll
            for (int ii = 0; ii < 2; ++ii)
#pragma unroll
                for (int j = 0; j < 4; ++j)
#pragma unroll
                    for (int r = 0; r < 4; ++r) {
                        int row = (wp * 2 + ii) * 16 + lq * 4 + r;
                        int col = hh * 64 + j * 16 + lm;
                        ATg[row * 512 + col] = f2b(oc[ii][j][r]);
                    }
        }
        __syncthreads();

        // ---- B: Wo GEMM. Hg = ATg @ WoT^T. N-strip 32/wave, K=512.
        {
            ffrag acc[4][2];
#pragma unroll
            for (int i = 0; i < 4; ++i)
#pragma unroll
                for (int j = 0; j < 2; ++j) acc[i][j] = (ffrag){0.f, 0.f, 0.f, 0.f};
#pragma unroll
            for (int k8 = 0; k8 < 16; ++k8) {
                bfrag af[4];
#pragma unroll
                for (int i = 0; i < 4; ++i)
                    af[i] = *(const bfrag*)&ATg[(i * 16 + lm) * 512 + k8 * 32 + lq * 8];
#pragma unroll
                for (int j = 0; j < 2; ++j) {
                    bfrag bw = *(const bfrag*)(WoT + (long long)(w * 32 + j * 16 + lm) * 512
                                               + k8 * 32 + lq * 8);
#pragma unroll
                    for (int i = 0; i < 4; ++i)
                        acc[i][j] = MFMA16(af[i], bw, acc[i][j]);
                }
            }
#pragma unroll
            for (int i = 0; i < 4; ++i)
#pragma unroll
                for (int j = 0; j < 2; ++j)
#pragma unroll
                    for (int r = 0; r < 4; ++r)
                        Hg[(i * 16 + lq * 4 + r) * 512 + w * 32 + j * 16 + lm] = f2b(acc[i][j][r]);
        }
        __syncthreads();

        // ---- C: LN1 in place: Hg = LN(curr + Hg), rows 0-49.
        for (int r = w; r < SEGL; r += 16) {
            const ushort_t* cr = ENC + (long long)n * 409600 + (long long)(t * 50 + r) * 512;
            uint4 a4 = *(const uint4*)&Hg[r * 512 + lane * 8];
            uint4 b4 = *(const uint4*)(cr + lane * 8);
            const unsigned* aa = (const unsigned*)&a4;
            const unsigned* bb = (const unsigned*)&b4;
            float x[8];
#pragma unroll
            for (int c = 0; c < 4; ++c) {
                union { unsigned u; float f; } alo, ahi, blo, bhi;
                alo.u = aa[c] << 16; ahi.u = aa[c] & 0xffff0000u;
                blo.u = bb[c] << 16; bhi.u = bb[c] & 0xffff0000u;
                x[2 * c]     = alo.f + blo.f;
                x[2 * c + 1] = ahi.f + bhi.f;
            }
            float s = 0.f, s2 = 0.f;
#pragma unroll
            for (int i = 0; i < 8; ++i) { s += x[i]; s2 = fmaf(x[i], x[i], s2); }
            for (int off = 32; off; off >>= 1) { s += __shfl_xor(s, off); s2 += __shfl_xor(s2, off); }
            float mean = s * (1.f / DMODEL);
            float var = s2 * (1.f / DMODEL) - mean * mean;
            float inv = rsqrtf(var + 1e-5f);
            float4 g0 = *(const float4*)(G1v + lane * 8);
            float4 g1 = *(const float4*)(G1v + lane * 8 + 4);
            float4 e0 = *(const float4*)(B1v + lane * 8);
            float4 e1 = *(const float4*)(B1v + lane * 8 + 4);
            ushort_t ob[8];
            ob[0] = f2b((x[0] - mean) * inv * g0.x + e0.x);
            ob[1] = f2b((x[1] - mean) * inv * g0.y + e0.y);
            ob[2] = f2b((x[2] - mean) * inv * g0.z + e0.z);
            ob[3] = f2b((x[3] - mean) * inv * g0.w + e0.w);
            ob[4] = f2b((x[4] - mean) * inv * g1.x + e1.x);
            ob[5] = f2b((x[5] - mean) * inv * g1.y + e1.y);
            ob[6] = f2b((x[6] - mean) * inv * g1.z + e1.z);
            ob[7] = f2b((x[7] - mean) * inv * g1.w + e1.w);
            *(uint4*)&Hg[r * 512 + lane * 8] = *(const uint4*)ob;
        }
        __syncthreads();

        // ---- D: FFN. 8 chunks of 256 ff-cols; F1 -> Mb (LDS) -> F2 acc in regs.
        ffrag fa[4][2];
#pragma unroll
        for (int i = 0; i < 4; ++i)
#pragma unroll
            for (int j = 0; j < 2; ++j) fa[i][j] = (ffrag){0.f, 0.f, 0.f, 0.f};
#pragma unroll 1
        for (int cc = 0; cc < 8; ++cc) {
            ffrag m1[4];
#pragma unroll
            for (int i = 0; i < 4; ++i) m1[i] = (ffrag){0.f, 0.f, 0.f, 0.f};
#pragma unroll
            for (int k8 = 0; k8 < 16; ++k8) {
                bfrag ah[4];
#pragma unroll
                for (int i = 0; i < 4; ++i)
                    ah[i] = *(const bfrag*)&Hg[(i * 16 + lm) * 512 + k8 * 32 + lq * 8];
                bfrag b1 = *(const bfrag*)(F1T + (long long)(cc * 256 + w * 16 + lm) * 512
                                           + k8 * 32 + lq * 8);
#pragma unroll
                for (int i = 0; i < 4; ++i) m1[i] = MFMA16(ah[i], b1, m1[i]);
            }
            __syncthreads();   // prior chunk's F2 reads of Mb done
#pragma unroll
            for (int i = 0; i < 4; ++i)
#pragma unroll
                for (int r = 0; r < 4; ++r)
                    Mb[(i * 16 + lq * 4 + r) * 264 + w * 16 + lm] = f2b(fmaxf(m1[i][r], 0.f));
            __syncthreads();
#pragma unroll
            for (int k8 = 0; k8 < 8; ++k8) {
                bfrag am[4];
#pragma unroll
                for (int i = 0; i < 4; ++i)
                    am[i] = *(const bfrag*)&Mb[(i * 16 + lm) * 264 + k8 * 32 + lq * 8];
#pragma unroll
                for (int j = 0; j < 2; ++j) {
                    bfrag b2 = *(const bfrag*)(F2T + (long long)(w * 32 + j * 16 + lm) * 2048
                                               + cc * 256 + k8 * 32 + lq * 8);
#pragma unroll
                    for (int i = 0; i < 4; ++i) fa[i][j] = MFMA16(am[i], b2, fa[i][j]);
                }
            }
        }
        // write ffn result to ATg (dead since Wo)
#pragma unroll
        for (int i = 0; i < 4; ++i)
#pragma unroll
            for (int j = 0; j < 2; ++j)
#pragma unroll
                for (int r = 0; r < 4; ++r)
                    ATg[(i * 16 + lq * 4 + r) * 512 + w * 32 + j * 16 + lm] = f2b(fa[i][j][r]);
        __syncthreads();

        // ---- E: LN2 -> P (LDS) rows 0-49; f32 out on last step.
        for (int r = w; r < SEGL; r += 16) {
            uint4 a4 = *(const uint4*)&Hg[r * 512 + lane * 8];
            uint4 b4 = *(const uint4*)&ATg[r * 512 + lane * 8];
            const unsigned* aa = (const unsigned*)&a4;
            const unsigned* bb = (const unsigned*)&b4;
            float x[8];
#pragma unroll
            for (int c = 0; c < 4; ++c) {
                union { unsigned u; float f; } alo, ahi, blo, bhi;
                alo.u = aa[c] << 16; ahi.u = aa[c] & 0xffff0000u;
                blo.u = bb[c] << 16; bhi.u = bb[c] & 0xffff0000u;
                x[2 * c]     = alo.f + blo.f;
                x[2 * c + 1] = ahi.f + bhi.f;
            }
            float s = 0.f, s2 = 0.f;
#pragma unroll
            for (int i = 0; i < 8; ++i) { s += x[i]; s2 = fmaf(x[i], x[i], s2); }
            for (int off = 32; off; off >>= 1) { s += __shfl_xor(s, off); s2 += __shfl_xor(s2, off); }
            float mean = s * (1.f / DMODEL);
            float var = s2 * (1.f / DMODEL) - mean * mean;
            float inv = rsqrtf(var + 1e-5f);
            float4 g0 = *(const float4*)(G2v + lane * 8);
            float4 g1 = *(const float4*)(G2v + lane * 8 + 4);
            float4 e0 = *(const float4*)(B2v + lane * 8);
            float4 e1 = *(const float4*)(B2v + lane * 8 + 4);
            float y[8];
            y[0] = (x[0] - mean) * inv * g0.x + e0.x;
            y[1] = (x[1] - mean) * inv * g0.y + e0.y;
            y[2] = (x[2] - mean) * inv * g0.z + e0.z;
            y[3] = (x[3] - mean) * inv * g0.w + e0.w;
            y[4] = (x[4] - mean) * inv * g1.x + e1.x;
            y[5] = (x[5] - mean) * inv * g1.y + e1.y;
            y[6] = (x[6] - mean) * inv * g1.z + e1.z;
            y[7] = (x[7] - mean) * inv * g1.w + e1.w;
            if (t == NT - 1) {
                float* o = out + ((long long)n * 50 + r) * 512 + lane * 8;
                *(float4*)o = *(float4*)&y[0];
                *(float4*)(o + 4) = *(float4*)&y[4];
            } else {
                ushort_t ob[8];
#pragma unroll
                for (int i = 0; i < 8; ++i) ob[i] = f2b(y[i]);
                *(uint4*)&Pb[r * 520 + lane * 8] = *(const uint4*)ob;
            }
        }
        __syncthreads();
    }
}

// ---------------------------------------------------------------------------
extern "C" void kernel_launch(void* const* d_in, const int* in_sizes, int n_in,
                              void* d_out, int out_size, void* d_ws, size_t ws_size,
                              hipStream_t stream)
{
    const float* seqs = (const float*)d_in[0];
    const int*   ends = (const int*)d_in[1];
    const float* eG1 = (const float*)d_in[7],  *eB1 = (const float*)d_in[8];
    const float* eG2 = (const float*)d_in[11], *eB2 = (const float*)d_in[12];
    const float* cG1 = (const float*)d_in[17], *cB1 = (const float*)d_in[18];
    const float* cG2 = (const float*)d_in[21], *cB2 = (const float*)d_in[22];
    float* out = (float*)d_out;

    const int G = (ws_size >= (size_t)470000000) ? 8 : 4;
    const long long CH = 1638400LL * G;

    ushort_t* ws = (ushort_t*)d_ws;
    const long long SEQROW = (long long)NT * SEGL * DMODEL;    // 409600
    ushort_t* SEQB = ws;
    ushort_t* WT   = SEQB + 26214400LL;
    ushort_t* ENC  = WT   + 6553600LL;
    ushort_t* BUF0 = ENC  + 26214400LL;
    ushort_t* QKV  = BUF0 + CH;
    ushort_t* BUF4 = QKV  + 3 * CH;
    ushort_t* BUF1 = BUF4 + CH;
    ushort_t* BUF2 = BUF1 + CH;
    ushort_t* MID  = BUF2 + CH;
    ushort_t* OUTB = MID  + 4 * CH;
    ushort_t* QALL = OUTB + 1638400LL;
    int*      lens = (int*)(QALL + 24576000LL);

    const ushort_t* eWinT = WT + 0;
    const ushort_t* WQKVe = WT + 262144;      // 1536 x 512
    const ushort_t* eWoT  = WT + 1048576;
    const ushort_t* eF1T  = WT + 1310720;     // 2048 x 512
    const ushort_t* eF2T  = WT + 2359296;     // 512 x 2048
    const ushort_t* cWqT  = WT + 3407872;
    const ushort_t* cKV   = WT + 3670016;     // 1024 x 512 (cWk^T | cWv^T)
    const ushort_t* cWoT  = WT + 4194304;
    const ushort_t* cF1T  = WT + 4456448;
    const ushort_t* cF2T  = WT + 5505024;

    struct WMap { int src; long long dst; int K, N; };
    const WMap wm[13] = {
        {2,  0,       512, 512},
        {3,  262144,  512, 512},
        {4,  524288,  512, 512},
        {5,  786432,  512, 512},
        {6,  1048576, 512, 512},
        {9,  1310720, 512, 2048},
        {10, 2359296, 2048, 512},
        {13, 3407872, 512, 512},
        {14, 3670016, 512, 512},
        {15, 3932160, 512, 512},
        {16, 4194304, 512, 512},
        {19, 4456448, 512, 2048},
        {20, 5505024, 2048, 512},
    };

    cvt_k<<<12800, 256, 0, stream>>>(seqs, SEQB, 26214400LL);
    for (int w = 0; w < 13; ++w) {
        dim3 g(wm[w].N / 32, wm[w].K / 32);
        wtrans_k<<<g, 256, 0, stream>>>((const float*)d_in[wm[w].src],
                                        WT + wm[w].dst, wm[w].K, wm[w].N);
    }
    lens_k<<<4, 256, 0, stream>>>(ends, lens);

    auto gemmL = [&](const ushort_t* A, int agrp, long long astr, const ushort_t* Bt,
                     ushort_t* C, int M, int N, int K, int relu) {
        dim3 g(N / 128, M / 128);
        mfma_gemm<128, 128, 2, 2><<<g, 256, 0, stream>>>(A, agrp, astr, Bt, C, M, N, K, relu);
    };

    // ---------------- Phase 1: all encoders, chunks of G segments ----------
    const int Mc = NB * G * SEGL;
    for (int c = 0; c < NT / G; ++c) {
        const int t0 = c * G;
        const ushort_t* Abase = SEQB + (long long)t0 * SEGL * DMODEL;
        ushort_t* ENCc = ENC + (long long)t0 * SEGL * DMODEL;
        gemmL(Abase, G * SEGL, SEQROW, eWinT, BUF0, Mc, 512, 512, 0);
        gemmL(BUF0, Mc, 0, WQKVe, QKV, Mc, 1536, 512, 0);
        attn_mfma_k<<<NB * G * NHEAD, 256, 0, stream>>>(
            QKV, 50LL * 1536, 1536, QKV + 512, QKV + 1024, 50LL * 1536, 1536,
            BUF4, lens, G, t0);
        gemmL(BUF4, Mc, 0, eWoT, BUF1, Mc, 512, 512, 0);
        add_ln_k<false><<<Mc / 4, 256, 0, stream>>>(BUF0, Mc, 0, BUF1, eG1, eB1,
                                                    BUF2, Mc, 0, Mc);
        gemmL(BUF2, Mc, 0, eF1T, MID, Mc, 2048, 512, 1);
        gemmL(MID, Mc, 0, eF2T, BUF1, Mc, 512, 2048, 0);
        add_ln_k<false><<<Mc / 4, 256, 0, stream>>>(BUF2, Mc, 0, BUF1, eG2, eB2,
                                                    ENCc, G * SEGL, SEQROW, Mc);
    }

    // Batched Q projections for ALL phase-2 steps
    gemmL(ENC + 25600, 750, SEQROW, cWqT, QALL, 48000, 512, 512, 0);

    // ---------------- Phase 2: 64 independent per-sequence chains ----------
    {
        constexpr int LDS_BYTES = (64 * 520 + 64 * 264) * 2;   // 100352
        static bool attr_set = false;
        if (!attr_set) {
            hipFuncSetAttribute((const void*)phase2_seq,
                                hipFuncAttributeMaxDynamicSharedMemorySize,
                                LDS_BYTES);
            attr_set = true;
        }
        phase2_seq<<<64, 1024, LDS_BYTES, stream>>>(
            ENC, QALL, cKV, cWoT, cF1T, cF2T,
            cG1, cB1, cG2, cB2, MID, out);
    }
}